// Round 14
// baseline (225.775 us; speedup 1.0000x reference)
//
#include <hip/hip_runtime.h>
#include <math.h>

#define S_LEN 2048
#define BATCH 4
#define FDIM 512
#define NHEAD 8
#define DHEAD 64
// Inputs fp32; output fp32. All GEMMs + attention in bf16 MFMA.

typedef unsigned short u16;
typedef short bf16x8 __attribute__((ext_vector_type(8)));
typedef float f32x4 __attribute__((ext_vector_type(4)));

__device__ __forceinline__ u16 f2bf(float f) {
    unsigned u = __float_as_uint(f);
    return (u16)((u + 0x7fffu + ((u >> 16) & 1u)) >> 16);  // RNE
}
__device__ __forceinline__ float bf2f(u16 u) {
    return __uint_as_float(((unsigned)u) << 16);
}
__device__ __forceinline__ ushort4 f2bf4(float4 t) {
    return (ushort4){f2bf(t.x), f2bf(t.y), f2bf(t.z), f2bf(t.w)};
}

// ---------- fused QKV projection GEMM (round-9/13 verbatim) ----------
__global__ __launch_bounds__(256) void gemm_qkv(
    const float* __restrict__ Aq, const float* __restrict__ Ak, const float* __restrict__ Av,
    const float* __restrict__ Wq, const float* __restrict__ Wk, const float* __restrict__ Wv,
    const float* __restrict__ bq, const float* __restrict__ bk, const float* __restrict__ bv,
    u16* __restrict__ Qb, u16* __restrict__ Kb, u16* __restrict__ Vtb, float qscale)
{
    __shared__ __align__(16) u16 pool[24576];
    const int tid = threadIdx.x;
    const int w = tid >> 6, lane = tid & 63;
    const int quad = lane >> 4, l16 = lane & 15;
    const int m0 = blockIdx.x * 128, n0 = blockIdx.y * 64, z = blockIdx.z;

    const float* A = (z == 0) ? Aq : (z == 1) ? Ak : Av;
    const float* W = (z == 0) ? Wq : (z == 1) ? Wk : Wv;
    const float* bias = (z == 0) ? bq : (z == 1) ? bk : bv;
    const float qs = (z == 0) ? qscale : 1.0f;

    const int srow = tid >> 4, scol = (tid & 15) * 4;

    f32x4 acc[2][4];
    #pragma unroll
    for (int rt = 0; rt < 2; rt++)
        #pragma unroll
        for (int nt = 0; nt < 4; nt++) acc[rt][nt] = (f32x4){0.f, 0.f, 0.f, 0.f};

    ushort4 ap[8], bp[4];
    auto loadT = [&](int k0) {
        #pragma unroll
        for (int it = 0; it < 8; it++) {
            int r = srow + it * 16;
            ap[it] = f2bf4(*(const float4*)(A + (size_t)(m0 + r) * FDIM + k0 + scol));
        }
        #pragma unroll
        for (int it = 0; it < 4; it++) {
            int r = srow + it * 16;
            bp[it] = f2bf4(*(const float4*)(W + (size_t)(n0 + r) * FDIM + k0 + scol));
        }
    };
    auto storeT = [&](int buf) {
        u16* Ab = pool + buf * 8192;
        u16* Bb = pool + 16384 + buf * 4096;
        #pragma unroll
        for (int it = 0; it < 8; it++) {
            int r = srow + it * 16;
            *(ushort4*)(Ab + r * 64 + (((scol >> 3) ^ (r & 7)) * 8) + (scol & 7)) = ap[it];
        }
        #pragma unroll
        for (int it = 0; it < 4; it++) {
            int r = srow + it * 16;
            *(ushort4*)(Bb + r * 64 + (((scol >> 3) ^ (r & 7)) * 8) + (scol & 7)) = bp[it];
        }
    };
    auto compute = [&](int buf) {
        const u16* Ab = pool + buf * 8192;
        const u16* Bb = pool + 16384 + buf * 4096;
        bf16x8 af[2][2];
        #pragma unroll
        for (int rt = 0; rt < 2; rt++) {
            const int row = w * 32 + rt * 16 + l16;
            af[rt][0] = *(const bf16x8*)(Ab + row * 64 + (((0 + quad) ^ (l16 & 7)) * 8));
            af[rt][1] = *(const bf16x8*)(Ab + row * 64 + (((4 + quad) ^ (l16 & 7)) * 8));
        }
        #pragma unroll
        for (int nt = 0; nt < 4; nt++) {
            const int rowb = nt * 16 + l16;
            bf16x8 b0 = *(const bf16x8*)(Bb + rowb * 64 + (((0 + quad) ^ (l16 & 7)) * 8));
            bf16x8 b1 = *(const bf16x8*)(Bb + rowb * 64 + (((4 + quad) ^ (l16 & 7)) * 8));
            #pragma unroll
            for (int rt = 0; rt < 2; rt++) {
                acc[rt][nt] = __builtin_amdgcn_mfma_f32_16x16x32_bf16(af[rt][0], b0, acc[rt][nt], 0, 0, 0);
                acc[rt][nt] = __builtin_amdgcn_mfma_f32_16x16x32_bf16(af[rt][1], b1, acc[rt][nt], 0, 0, 0);
            }
        }
    };

    loadT(0); storeT(0); __syncthreads();
    int cur = 0;
    #pragma unroll
    for (int i = 0; i < 8; i++) {
        if (i < 7) loadT((i + 1) * 64);
        compute(cur);
        if (i < 7) { storeT(1 - cur); cur = 1 - cur; __syncthreads(); }
    }

    float bvv[4];
    #pragma unroll
    for (int nt = 0; nt < 4; nt++) bvv[nt] = bias[n0 + nt * 16 + l16];
    const int h = blockIdx.y;
    u16* Epi = pool;   // [4*32][40]

    if (z < 2) {
        u16* outB = (z == 0) ? Qb : Kb;
        const float NEG_LN1E4_32 = -0.2878231366242558f;
        float th[4];
        #pragma unroll
        for (int nt = 0; nt < 4; nt++)
            th[nt] = expf(NEG_LN1E4_32 * (float)(nt * 8 + (l16 >> 1)));
        #pragma unroll
        for (int pass = 0; pass < 2; pass++) {
            #pragma unroll
            for (int rt = 0; rt < 2; rt++) {
                const int s = (m0 >> 2) + w * 8 + rt * 4 + quad;
                #pragma unroll
                for (int nn = 0; nn < 2; nn++) {
                    const int nt = pass * 2 + nn;
                    float c, sn;
                    __sincosf((float)s * th[nt], &sn, &c);
                    #pragma unroll
                    for (int i = 0; i < 4; i++) {
                        float vv = fmaxf(acc[rt][nt][i] + bvv[nt], 0.f);
                        float t = __shfl_xor(vv, 1);
                        vv = (l16 & 1) ? (t * sn + vv * c) : (vv * c - t * sn);
                        Epi[(w * 32 + rt * 16 + quad * 4 + i) * 40 + nn * 16 + l16] = f2bf(vv * qs);
                    }
                }
            }
            asm volatile("s_waitcnt lgkmcnt(0)" ::: "memory");
            const int mloc = lane >> 1, seg = lane & 1;
            const int m = m0 + w * 32 + mloc;
            const int s2 = m >> 2, b = m & 3;
            const size_t dst = ((size_t)(b * 8 + h) * S_LEN + s2) * DHEAD + pass * 32 + seg * 16;
            uint4 t0 = *(const uint4*)&Epi[(w * 32 + mloc) * 40 + seg * 16];
            uint4 t1 = *(const uint4*)&Epi[(w * 32 + mloc) * 40 + seg * 16 + 8];
            *(uint4*)(outB + dst)     = t0;
            *(uint4*)(outB + dst + 8) = t1;
            asm volatile("s_waitcnt lgkmcnt(0)" ::: "memory");
        }
    } else {
        #pragma unroll
        for (int pass = 0; pass < 2; pass++) {
            #pragma unroll
            for (int rt = 0; rt < 2; rt++)
                #pragma unroll
                for (int nn = 0; nn < 2; nn++) {
                    const int nt = pass * 2 + nn;
                    #pragma unroll
                    for (int i = 0; i < 4; i++) {
                        float vv = fmaxf(acc[rt][nt][i] + bvv[nt], 0.f);
                        Epi[(w * 32 + rt * 16 + quad * 4 + i) * 40 + nn * 16 + l16] = f2bf(vv);
                    }
                }
            asm volatile("s_waitcnt lgkmcnt(0)" ::: "memory");
            const int half = lane >> 5, dp = lane & 31;
            const int d = pass * 32 + dp;
            const int sBase = (m0 >> 2) + w * 8;
            #pragma unroll
            for (int bb = 0; bb < 2; bb++) {
                const int b = half * 2 + bb;
                u16 tmp[8];
                #pragma unroll
                for (int sl = 0; sl < 8; sl++)
                    tmp[sl] = Epi[(w * 32 + sl * 4 + b) * 40 + dp];
                *(uint4*)(Vtb + ((size_t)(b * 8 + h) * DHEAD + d) * S_LEN + sBase) =
                    *(const uint4*)tmp;
            }
            asm volatile("s_waitcnt lgkmcnt(0)" ::: "memory");
        }
    }
}

// ---------- output GEMM: 64x64 tile, grid 1024 blocks -> 4 blocks/CU ----------
__global__ __launch_bounds__(256) void gemm_out(
    const u16* __restrict__ A, const float* __restrict__ W,
    const float* __restrict__ bias, float* __restrict__ outF)
{
    __shared__ __align__(16) u16 pool[16384];   // A0 A1 B0 B1, 4096 u16 each
    const int tid = threadIdx.x;
    const int w = tid >> 6, lane = tid & 63;
    const int quad = lane >> 4, l16 = lane & 15;
    const int m0 = blockIdx.x * 64, n0 = blockIdx.y * 64;

    const int srow = tid >> 4, scol = (tid & 15) * 4;   // W staging (fp32)
    int rr[2], gg[2];                                   // A staging (bf16 uint4)
    #pragma unroll
    for (int it = 0; it < 2; it++) { int c = tid + it * 256; rr[it] = c >> 3; gg[it] = c & 7; }

    f32x4 acc[4];
    #pragma unroll
    for (int nt = 0; nt < 4; nt++) acc[nt] = (f32x4){0.f, 0.f, 0.f, 0.f};

    uint4 av[2]; ushort4 bp[4];
    auto loadT = [&](int k0) {
        #pragma unroll
        for (int it = 0; it < 2; it++)
            av[it] = *(const uint4*)(A + (size_t)(m0 + rr[it]) * FDIM + k0 + gg[it] * 8);
        #pragma unroll
        for (int it = 0; it < 4; it++) {
            int r = srow + it * 16;
            bp[it] = f2bf4(*(const float4*)(W + (size_t)(n0 + r) * FDIM + k0 + scol));
        }
    };
    auto storeT = [&](int buf) {
        u16* Ab = pool + buf * 4096;
        u16* Bb = pool + 8192 + buf * 4096;
        #pragma unroll
        for (int it = 0; it < 2; it++)
            *(uint4*)(Ab + rr[it] * 64 + ((gg[it] ^ (rr[it] & 7)) * 8)) = av[it];
        #pragma unroll
        for (int it = 0; it < 4; it++) {
            int r = srow + it * 16;
            *(ushort4*)(Bb + r * 64 + (((scol >> 3) ^ (r & 7)) * 8) + (scol & 7)) = bp[it];
        }
    };
    auto compute = [&](int buf) {
        const u16* Ab = pool + buf * 4096;
        const u16* Bb = pool + 8192 + buf * 4096;
        const int row = w * 16 + l16;
        bf16x8 af0 = *(const bf16x8*)(Ab + row * 64 + (((0 + quad) ^ (l16 & 7)) * 8));
        bf16x8 af1 = *(const bf16x8*)(Ab + row * 64 + (((4 + quad) ^ (l16 & 7)) * 8));
        #pragma unroll
        for (int nt = 0; nt < 4; nt++) {
            const int rowb = nt * 16 + l16;
            bf16x8 b0 = *(const bf16x8*)(Bb + rowb * 64 + (((0 + quad) ^ (l16 & 7)) * 8));
            bf16x8 b1 = *(const bf16x8*)(Bb + rowb * 64 + (((4 + quad) ^ (l16 & 7)) * 8));
            acc[nt] = __builtin_amdgcn_mfma_f32_16x16x32_bf16(af0, b0, acc[nt], 0, 0, 0);
            acc[nt] = __builtin_amdgcn_mfma_f32_16x16x32_bf16(af1, b1, acc[nt], 0, 0, 0);
        }
    };

    loadT(0); storeT(0); __syncthreads();
    int cur = 0;
    #pragma unroll
    for (int i = 0; i < 8; i++) {
        if (i < 7) loadT((i + 1) * 64);
        compute(cur);
        if (i < 7) { storeT(1 - cur); cur = 1 - cur; __syncthreads(); }
    }

    float bvv[4];
    #pragma unroll
    for (int nt = 0; nt < 4; nt++) bvv[nt] = bias[n0 + nt * 16 + l16];
    #pragma unroll
    for (int nt = 0; nt < 4; nt++)
        #pragma unroll
        for (int i = 0; i < 4; i++) {
            const int m = m0 + w * 16 + quad * 4 + i;
            outF[(size_t)m * FDIM + n0 + nt * 16 + l16] =
                fmaxf(acc[nt][i] + bvv[nt], 0.f);
        }
}

// ---------- MFMA flash v5: row-sum l via ones-MFMA (matrix pipe, not VALU) ----------
__global__ __launch_bounds__(256, 4) void flash_attn_mfma(
    const u16* __restrict__ Q, const u16* __restrict__ K, const u16* __restrict__ Vt,
    u16* __restrict__ Opart, float* __restrict__ Lpart)
{
    __shared__ __align__(16) u16 pool[16384];
    const int tid = threadIdx.x;
    const int w = tid >> 6, lane = tid & 63;
    const int quad = lane >> 4, l16 = lane & 15;
    const int s0 = blockIdx.x * 128, n = blockIdx.y, kh = blockIdx.z;

    const size_t baseQ = ((size_t)n * S_LEN + s0) * DHEAD;
    const size_t baseK = ((size_t)n * S_LEN + kh * 1024) * DHEAD;
    const size_t baseV = (size_t)n * DHEAD * S_LEN + kh * 1024;

    #pragma unroll
    for (int it = 0; it < 4; it++) {
        int c = tid + it * 256, r = c >> 3, g = c & 7;
        *(uint4*)(pool + r * 64 + ((g ^ (r & 7)) * 8)) =
            *(const uint4*)(Q + baseQ + r * DHEAD + g * 8);
    }
    __syncthreads();
    const int xa = ((0 + quad) ^ (l16 & 7)) * 8;
    const int xb = ((4 + quad) ^ (l16 & 7)) * 8;
    bf16x8 qa[2][2];
    #pragma unroll
    for (int s = 0; s < 2; s++) {
        const int row = w * 32 + s * 16 + l16;
        qa[s][0] = *(const bf16x8*)(pool + row * 64 + xa);
        qa[s][1] = *(const bf16x8*)(pool + row * 64 + xb);
    }
    __syncthreads();

    // constant all-ones A-operand for the row-sum MFMA (bf16 1.0 = 0x3F80)
    union { unsigned u[4]; bf16x8 v; } onesA;
    #pragma unroll
    for (int t = 0; t < 4; t++) onesA.u[t] = 0x3F803F80u;

    f32x4 accO[2][4], accL[2];
    #pragma unroll
    for (int s = 0; s < 2; s++) {
        #pragma unroll
        for (int dt = 0; dt < 4; dt++) accO[s][dt] = (f32x4){0.f, 0.f, 0.f, 0.f};
        accL[s] = (f32x4){0.f, 0.f, 0.f, 0.f};
    }

    const int sr = tid >> 3, sg = tid & 7;
    const int Hh = sg >> 2, vOff = ((sg >> 1) & 1) * 4;
    const int o1 = (2 * sg) & 3, o2 = (2 * sg + 1) & 3;
    uint4 kc[2], vc[2];
    auto loadKV = [&](int k0) {
        kc[0] = *(const uint4*)(K + baseK + (size_t)(k0 + sr) * DHEAD + sg * 8);
        kc[1] = *(const uint4*)(K + baseK + (size_t)(k0 + sr + 32) * DHEAD + sg * 8);
        vc[0] = *(const uint4*)(Vt + baseV + (size_t)sr * S_LEN + k0 + sg * 8);
        vc[1] = *(const uint4*)(Vt + baseV + (size_t)(sr + 32) * S_LEN + k0 + sg * 8);
    };
    auto storeKV = [&](int buf) {
        u16* Kb = pool + buf * 8192;
        u16* Vb = pool + 4096 + buf * 8192;
        const int swk = (sg ^ (sr & 7)) * 8;
        *(uint4*)(Kb + sr * 64 + swk)        = kc[0];
        *(uint4*)(Kb + (sr + 32) * 64 + swk) = kc[1];
        const int a1 = ((Hh * 4 + o1) ^ (sr & 7)) * 8 + vOff;
        const int a2 = ((Hh * 4 + o2) ^ (sr & 7)) * 8 + vOff;
        *(uint2*)(Vb + sr * 64 + a1)        = (uint2){vc[0].x, vc[0].y};
        *(uint2*)(Vb + sr * 64 + a2)        = (uint2){vc[0].z, vc[0].w};
        *(uint2*)(Vb + (sr + 32) * 64 + a1) = (uint2){vc[1].x, vc[1].y};
        *(uint2*)(Vb + (sr + 32) * 64 + a2) = (uint2){vc[1].z, vc[1].w};
    };

    loadKV(0);
    storeKV(0);
    __syncthreads();

    for (int i = 0; i < 16; i++) {
        const int buf = i & 1;
        const u16* Kbf = pool + buf * 8192;
        const u16* Vbf = pool + 4096 + buf * 8192;
        if (i < 15) loadKV((i + 1) * 64);

        f32x4 sc[2][4];
        #pragma unroll
        for (int kt = 0; kt < 4; kt++) {
            const int kr = kt * 16 + l16;
            bf16x8 kb0 = *(const bf16x8*)(Kbf + kr * 64 + xa);
            bf16x8 kb1 = *(const bf16x8*)(Kbf + kr * 64 + xb);
            #pragma unroll
            for (int s = 0; s < 2; s++) {
                f32x4 z = (f32x4){0.f, 0.f, 0.f, 0.f};
                z = __builtin_amdgcn_mfma_f32_16x16x32_bf16(kb0, qa[s][0], z, 0, 0, 0);
                z = __builtin_amdgcn_mfma_f32_16x16x32_bf16(kb1, qa[s][1], z, 0, 0, 0);
                sc[s][kt] = z;
            }
        }

        union { unsigned u[4]; bf16x8 v; } pb[2][2];
        #pragma unroll
        for (int s = 0; s < 2; s++) {
            #pragma unroll
            for (int kt = 0; kt < 4; kt++) {
                float p0 = __builtin_amdgcn_exp2f(sc[s][kt][0] - 20.0f);
                float p1 = __builtin_amdgcn_exp2f(sc[s][kt][1] - 20.0f);
                float p2 = __builtin_amdgcn_exp2f(sc[s][kt][2] - 20.0f);
                float p3 = __builtin_amdgcn_exp2f(sc[s][kt][3] - 20.0f);
                pb[s][kt >> 1].u[(kt & 1) * 2 + 0] =
                    __builtin_amdgcn_perm(__float_as_uint(p1), __float_as_uint(p0), 0x07060302u);
                pb[s][kt >> 1].u[(kt & 1) * 2 + 1] =
                    __builtin_amdgcn_perm(__float_as_uint(p3), __float_as_uint(p2), 0x07060302u);
            }
        }

        // row-sums on the matrix pipe: accL = 1 · P^T  (all 4 regs equal l per col)
        #pragma unroll
        for (int s = 0; s < 2; s++) {
            accL[s] = __builtin_amdgcn_mfma_f32_16x16x32_bf16(onesA.v, pb[s][0].v, accL[s], 0, 0, 0);
            accL[s] = __builtin_amdgcn_mfma_f32_16x16x32_bf16(onesA.v, pb[s][1].v, accL[s], 0, 0, 0);
        }

        #pragma unroll
        for (int dt = 0; dt < 4; dt++) {
            const int vr = dt * 16 + l16;
            bf16x8 va0 = *(const bf16x8*)(Vbf + vr * 64 + xa);
            bf16x8 va1 = *(const bf16x8*)(Vbf + vr * 64 + xb);
            #pragma unroll
            for (int s = 0; s < 2; s++) {
                accO[s][dt] = __builtin_amdgcn_mfma_f32_16x16x32_bf16(va0, pb[s][0].v, accO[s][dt], 0, 0, 0);
                accO[s][dt] = __builtin_amdgcn_mfma_f32_16x16x32_bf16(va1, pb[s][1].v, accO[s][dt], 0, 0, 0);
            }
        }

        if (i < 15) { storeKV(1 - buf); __syncthreads(); }
    }

    // ---- epilogue: bf16 O-partial + fp32 row-sum partial (l = accL[s][0], no shuffles) ----
    const int bI = n >> 3, h = n & 7;
    u16* Ob = Opart + (size_t)kh * (8192 * 512);
    #pragma unroll
    for (int s = 0; s < 2; s++) {
        const int qg = s0 + w * 32 + s * 16 + l16;
        if (quad == 0)
            Lpart[(size_t)kh * 65536 + n * 2048 + qg] = accL[s][0];
        const size_t base = (size_t)(qg * BATCH + bI) * FDIM + h * DHEAD;
        #pragma unroll
        for (int dt = 0; dt < 4; dt++) {
            ushort4 st = {f2bf(accO[s][dt][0]), f2bf(accO[s][dt][1]),
                          f2bf(accO[s][dt][2]), f2bf(accO[s][dt][3])};
            *(ushort4*)(Ob + base + dt * 16 + quad * 4) = st;
        }
    }
}

// ---------- combine split-K partials (round-13 verbatim) ----------
__global__ __launch_bounds__(256) void combine_k(
    const u16* __restrict__ O, const float* __restrict__ L, u16* __restrict__ Yb)
{
    const int idx = blockIdx.x * 256 + threadIdx.x;   // 4-elem group index
    const int m = idx >> 7, c4 = idx & 127;
    const int g = c4 * 4, h = g >> 6;
    const int q = m >> 2, b = m & 3, n = b * 8 + h;
    const float l = L[n * 2048 + q] + L[65536 + n * 2048 + q];
    const float inv = 1.0f / l;
    const ushort4 o0 = *(const ushort4*)(O + (size_t)m * 512 + g);
    const ushort4 o1 = *(const ushort4*)(O + 4194304u + (size_t)m * 512 + g);
    ushort4 r = {f2bf((bf2f(o0.x) + bf2f(o1.x)) * inv),
                 f2bf((bf2f(o0.y) + bf2f(o1.y)) * inv),
                 f2bf((bf2f(o0.z) + bf2f(o1.z)) * inv),
                 f2bf((bf2f(o0.w) + bf2f(o1.w)) * inv)};
    *(ushort4*)(Yb + (size_t)m * 512 + g) = r;
}

extern "C" void kernel_launch(void* const* d_in, const int* in_sizes, int n_in,
                              void* d_out, int out_size, void* d_ws, size_t ws_size,
                              hipStream_t stream) {
    const float* q  = (const float*)d_in[0];
    const float* k  = (const float*)d_in[1];
    const float* v  = (const float*)d_in[2];
    const float* Wq = (const float*)d_in[3];
    const float* bq = (const float*)d_in[4];
    const float* Wk = (const float*)d_in[5];
    const float* bk = (const float*)d_in[6];
    const float* Wv = (const float*)d_in[7];
    const float* bv = (const float*)d_in[8];
    const float* Wo = (const float*)d_in[9];
    const float* bo = (const float*)d_in[10];
    float* out = (float*)d_out;

    const int NIN = S_LEN * BATCH * FDIM;    // 4194304
    u16* p = (u16*)d_ws;
    u16* Qb  = p;             p += NIN;      // reused as Yb after flash
    u16* Kb  = p;             p += NIN;
    u16* Vtb = p;             p += NIN;
    u16* Opart = p;           p += 2 * NIN;  // 2 x 4194304 bf16
    float* Lpart = (float*)p;                // 2 x 65536 fp32
    u16* Yb = Qb;                            // alias: Qb dead after flash

    const float QSCALE = 0.125f * 1.4426950408889634f;  // 1/sqrt(D) * log2(e)

    dim3 blk(256);
    dim3 gQKV(S_LEN * BATCH / 128, FDIM / 64, 3);   // (64, 8, 3)
    gemm_qkv<<<gQKV, blk, 0, stream>>>(q, k, v, Wq, Wk, Wv, bq, bk, bv,
                                       Qb, Kb, Vtb, QSCALE);

    dim3 gAttn(S_LEN / 128, 32, 2);                 // (16, 32, 2) = 1024 blocks
    flash_attn_mfma<<<gAttn, blk, 0, stream>>>(Qb, Kb, Vtb, Opart, Lpart);

    combine_k<<<4096, blk, 0, stream>>>(Opart, Lpart, Yb);

    dim3 gOut(S_LEN * BATCH / 64, FDIM / 64);       // (128, 8) = 1024 blocks
    gemm_out<<<gOut, blk, 0, stream>>>(Yb, Wo, bo, out);
}

// Round 15
// 220.265 us; speedup vs baseline: 1.0250x; 1.0250x over previous
//
#include <hip/hip_runtime.h>
#include <math.h>

#define S_LEN 2048
#define BATCH 4
#define FDIM 512
#define NHEAD 8
#define DHEAD 64
// Inputs fp32; output fp32. All GEMMs + attention in bf16 MFMA.
// Best-of: round-13 GEMMs (128x64) + round-14 flash v5 (ones-MFMA row-sum).

typedef unsigned short u16;
typedef short bf16x8 __attribute__((ext_vector_type(8)));
typedef float f32x4 __attribute__((ext_vector_type(4)));

__device__ __forceinline__ u16 f2bf(float f) {
    unsigned u = __float_as_uint(f);
    return (u16)((u + 0x7fffu + ((u >> 16) & 1u)) >> 16);  // RNE
}
__device__ __forceinline__ float bf2f(u16 u) {
    return __uint_as_float(((unsigned)u) << 16);
}
__device__ __forceinline__ ushort4 f2bf4(float4 t) {
    return (ushort4){f2bf(t.x), f2bf(t.y), f2bf(t.z), f2bf(t.w)};
}

// ---------- fused QKV projection GEMM (round-9/13 verbatim) ----------
__global__ __launch_bounds__(256) void gemm_qkv(
    const float* __restrict__ Aq, const float* __restrict__ Ak, const float* __restrict__ Av,
    const float* __restrict__ Wq, const float* __restrict__ Wk, const float* __restrict__ Wv,
    const float* __restrict__ bq, const float* __restrict__ bk, const float* __restrict__ bv,
    u16* __restrict__ Qb, u16* __restrict__ Kb, u16* __restrict__ Vtb, float qscale)
{
    __shared__ __align__(16) u16 pool[24576];
    const int tid = threadIdx.x;
    const int w = tid >> 6, lane = tid & 63;
    const int quad = lane >> 4, l16 = lane & 15;
    const int m0 = blockIdx.x * 128, n0 = blockIdx.y * 64, z = blockIdx.z;

    const float* A = (z == 0) ? Aq : (z == 1) ? Ak : Av;
    const float* W = (z == 0) ? Wq : (z == 1) ? Wk : Wv;
    const float* bias = (z == 0) ? bq : (z == 1) ? bk : bv;
    const float qs = (z == 0) ? qscale : 1.0f;

    const int srow = tid >> 4, scol = (tid & 15) * 4;

    f32x4 acc[2][4];
    #pragma unroll
    for (int rt = 0; rt < 2; rt++)
        #pragma unroll
        for (int nt = 0; nt < 4; nt++) acc[rt][nt] = (f32x4){0.f, 0.f, 0.f, 0.f};

    ushort4 ap[8], bp[4];
    auto loadT = [&](int k0) {
        #pragma unroll
        for (int it = 0; it < 8; it++) {
            int r = srow + it * 16;
            ap[it] = f2bf4(*(const float4*)(A + (size_t)(m0 + r) * FDIM + k0 + scol));
        }
        #pragma unroll
        for (int it = 0; it < 4; it++) {
            int r = srow + it * 16;
            bp[it] = f2bf4(*(const float4*)(W + (size_t)(n0 + r) * FDIM + k0 + scol));
        }
    };
    auto storeT = [&](int buf) {
        u16* Ab = pool + buf * 8192;
        u16* Bb = pool + 16384 + buf * 4096;
        #pragma unroll
        for (int it = 0; it < 8; it++) {
            int r = srow + it * 16;
            *(ushort4*)(Ab + r * 64 + (((scol >> 3) ^ (r & 7)) * 8) + (scol & 7)) = ap[it];
        }
        #pragma unroll
        for (int it = 0; it < 4; it++) {
            int r = srow + it * 16;
            *(ushort4*)(Bb + r * 64 + (((scol >> 3) ^ (r & 7)) * 8) + (scol & 7)) = bp[it];
        }
    };
    auto compute = [&](int buf) {
        const u16* Ab = pool + buf * 8192;
        const u16* Bb = pool + 16384 + buf * 4096;
        bf16x8 af[2][2];
        #pragma unroll
        for (int rt = 0; rt < 2; rt++) {
            const int row = w * 32 + rt * 16 + l16;
            af[rt][0] = *(const bf16x8*)(Ab + row * 64 + (((0 + quad) ^ (l16 & 7)) * 8));
            af[rt][1] = *(const bf16x8*)(Ab + row * 64 + (((4 + quad) ^ (l16 & 7)) * 8));
        }
        #pragma unroll
        for (int nt = 0; nt < 4; nt++) {
            const int rowb = nt * 16 + l16;
            bf16x8 b0 = *(const bf16x8*)(Bb + rowb * 64 + (((0 + quad) ^ (l16 & 7)) * 8));
            bf16x8 b1 = *(const bf16x8*)(Bb + rowb * 64 + (((4 + quad) ^ (l16 & 7)) * 8));
            #pragma unroll
            for (int rt = 0; rt < 2; rt++) {
                acc[rt][nt] = __builtin_amdgcn_mfma_f32_16x16x32_bf16(af[rt][0], b0, acc[rt][nt], 0, 0, 0);
                acc[rt][nt] = __builtin_amdgcn_mfma_f32_16x16x32_bf16(af[rt][1], b1, acc[rt][nt], 0, 0, 0);
            }
        }
    };

    loadT(0); storeT(0); __syncthreads();
    int cur = 0;
    #pragma unroll
    for (int i = 0; i < 8; i++) {
        if (i < 7) loadT((i + 1) * 64);
        compute(cur);
        if (i < 7) { storeT(1 - cur); cur = 1 - cur; __syncthreads(); }
    }

    float bvv[4];
    #pragma unroll
    for (int nt = 0; nt < 4; nt++) bvv[nt] = bias[n0 + nt * 16 + l16];
    const int h = blockIdx.y;
    u16* Epi = pool;   // [4*32][40]

    if (z < 2) {
        u16* outB = (z == 0) ? Qb : Kb;
        const float NEG_LN1E4_32 = -0.2878231366242558f;
        float th[4];
        #pragma unroll
        for (int nt = 0; nt < 4; nt++)
            th[nt] = expf(NEG_LN1E4_32 * (float)(nt * 8 + (l16 >> 1)));
        #pragma unroll
        for (int pass = 0; pass < 2; pass++) {
            #pragma unroll
            for (int rt = 0; rt < 2; rt++) {
                const int s = (m0 >> 2) + w * 8 + rt * 4 + quad;
                #pragma unroll
                for (int nn = 0; nn < 2; nn++) {
                    const int nt = pass * 2 + nn;
                    float c, sn;
                    __sincosf((float)s * th[nt], &sn, &c);
                    #pragma unroll
                    for (int i = 0; i < 4; i++) {
                        float vv = fmaxf(acc[rt][nt][i] + bvv[nt], 0.f);
                        float t = __shfl_xor(vv, 1);
                        vv = (l16 & 1) ? (t * sn + vv * c) : (vv * c - t * sn);
                        Epi[(w * 32 + rt * 16 + quad * 4 + i) * 40 + nn * 16 + l16] = f2bf(vv * qs);
                    }
                }
            }
            asm volatile("s_waitcnt lgkmcnt(0)" ::: "memory");
            const int mloc = lane >> 1, seg = lane & 1;
            const int m = m0 + w * 32 + mloc;
            const int s2 = m >> 2, b = m & 3;
            const size_t dst = ((size_t)(b * 8 + h) * S_LEN + s2) * DHEAD + pass * 32 + seg * 16;
            uint4 t0 = *(const uint4*)&Epi[(w * 32 + mloc) * 40 + seg * 16];
            uint4 t1 = *(const uint4*)&Epi[(w * 32 + mloc) * 40 + seg * 16 + 8];
            *(uint4*)(outB + dst)     = t0;
            *(uint4*)(outB + dst + 8) = t1;
            asm volatile("s_waitcnt lgkmcnt(0)" ::: "memory");
        }
    } else {
        #pragma unroll
        for (int pass = 0; pass < 2; pass++) {
            #pragma unroll
            for (int rt = 0; rt < 2; rt++)
                #pragma unroll
                for (int nn = 0; nn < 2; nn++) {
                    const int nt = pass * 2 + nn;
                    #pragma unroll
                    for (int i = 0; i < 4; i++) {
                        float vv = fmaxf(acc[rt][nt][i] + bvv[nt], 0.f);
                        Epi[(w * 32 + rt * 16 + quad * 4 + i) * 40 + nn * 16 + l16] = f2bf(vv);
                    }
                }
            asm volatile("s_waitcnt lgkmcnt(0)" ::: "memory");
            const int half = lane >> 5, dp = lane & 31;
            const int d = pass * 32 + dp;
            const int sBase = (m0 >> 2) + w * 8;
            #pragma unroll
            for (int bb = 0; bb < 2; bb++) {
                const int b = half * 2 + bb;
                u16 tmp[8];
                #pragma unroll
                for (int sl = 0; sl < 8; sl++)
                    tmp[sl] = Epi[(w * 32 + sl * 4 + b) * 40 + dp];
                *(uint4*)(Vtb + ((size_t)(b * 8 + h) * DHEAD + d) * S_LEN + sBase) =
                    *(const uint4*)tmp;
            }
            asm volatile("s_waitcnt lgkmcnt(0)" ::: "memory");
        }
    }
}

// ---------- output GEMM (round-13 verbatim: 128x64 tile) ----------
__global__ __launch_bounds__(256) void gemm_out(
    const u16* __restrict__ A, const float* __restrict__ W,
    const float* __restrict__ bias, float* __restrict__ outF)
{
    __shared__ __align__(16) u16 pool[24576];
    const int tid = threadIdx.x;
    const int w = tid >> 6, lane = tid & 63;
    const int quad = lane >> 4, l16 = lane & 15;
    const int m0 = blockIdx.x * 128, n0 = blockIdx.y * 64;

    const int srow = tid >> 4, scol = (tid & 15) * 4;
    int rr[4], gg[4];
    #pragma unroll
    for (int it = 0; it < 4; it++) { int c = tid + it * 256; rr[it] = c >> 3; gg[it] = c & 7; }

    f32x4 acc[2][4];
    #pragma unroll
    for (int rt = 0; rt < 2; rt++)
        #pragma unroll
        for (int nt = 0; nt < 4; nt++) acc[rt][nt] = (f32x4){0.f, 0.f, 0.f, 0.f};

    uint4 av[4]; ushort4 bp[4];
    auto loadT = [&](int k0) {
        #pragma unroll
        for (int it = 0; it < 4; it++)
            av[it] = *(const uint4*)(A + (size_t)(m0 + rr[it]) * FDIM + k0 + gg[it] * 8);
        #pragma unroll
        for (int it = 0; it < 4; it++) {
            int r = srow + it * 16;
            bp[it] = f2bf4(*(const float4*)(W + (size_t)(n0 + r) * FDIM + k0 + scol));
        }
    };
    auto storeT = [&](int buf) {
        u16* Ab = pool + buf * 8192;
        u16* Bb = pool + 16384 + buf * 4096;
        #pragma unroll
        for (int it = 0; it < 4; it++)
            *(uint4*)(Ab + rr[it] * 64 + ((gg[it] ^ (rr[it] & 7)) * 8)) = av[it];
        #pragma unroll
        for (int it = 0; it < 4; it++) {
            int r = srow + it * 16;
            *(ushort4*)(Bb + r * 64 + (((scol >> 3) ^ (r & 7)) * 8) + (scol & 7)) = bp[it];
        }
    };
    auto compute = [&](int buf) {
        const u16* Ab = pool + buf * 8192;
        const u16* Bb = pool + 16384 + buf * 4096;
        bf16x8 af[2][2];
        #pragma unroll
        for (int rt = 0; rt < 2; rt++) {
            const int row = w * 32 + rt * 16 + l16;
            af[rt][0] = *(const bf16x8*)(Ab + row * 64 + (((0 + quad) ^ (l16 & 7)) * 8));
            af[rt][1] = *(const bf16x8*)(Ab + row * 64 + (((4 + quad) ^ (l16 & 7)) * 8));
        }
        #pragma unroll
        for (int nt = 0; nt < 4; nt++) {
            const int rowb = nt * 16 + l16;
            bf16x8 b0 = *(const bf16x8*)(Bb + rowb * 64 + (((0 + quad) ^ (l16 & 7)) * 8));
            bf16x8 b1 = *(const bf16x8*)(Bb + rowb * 64 + (((4 + quad) ^ (l16 & 7)) * 8));
            #pragma unroll
            for (int rt = 0; rt < 2; rt++) {
                acc[rt][nt] = __builtin_amdgcn_mfma_f32_16x16x32_bf16(af[rt][0], b0, acc[rt][nt], 0, 0, 0);
                acc[rt][nt] = __builtin_amdgcn_mfma_f32_16x16x32_bf16(af[rt][1], b1, acc[rt][nt], 0, 0, 0);
            }
        }
    };

    loadT(0); storeT(0); __syncthreads();
    int cur = 0;
    #pragma unroll
    for (int i = 0; i < 8; i++) {
        if (i < 7) loadT((i + 1) * 64);
        compute(cur);
        if (i < 7) { storeT(1 - cur); cur = 1 - cur; __syncthreads(); }
    }

    float bvv[4];
    #pragma unroll
    for (int nt = 0; nt < 4; nt++) bvv[nt] = bias[n0 + nt * 16 + l16];
    #pragma unroll
    for (int rt = 0; rt < 2; rt++)
        #pragma unroll
        for (int nt = 0; nt < 4; nt++)
            #pragma unroll
            for (int i = 0; i < 4; i++) {
                const int m = m0 + w * 32 + rt * 16 + quad * 4 + i;
                outF[(size_t)m * FDIM + n0 + nt * 16 + l16] =
                    fmaxf(acc[rt][nt][i] + bvv[nt], 0.f);
            }
}

// ---------- MFMA flash v5 (round-14 verbatim: ones-MFMA row-sum) ----------
__global__ __launch_bounds__(256, 4) void flash_attn_mfma(
    const u16* __restrict__ Q, const u16* __restrict__ K, const u16* __restrict__ Vt,
    u16* __restrict__ Opart, float* __restrict__ Lpart)
{
    __shared__ __align__(16) u16 pool[16384];
    const int tid = threadIdx.x;
    const int w = tid >> 6, lane = tid & 63;
    const int quad = lane >> 4, l16 = lane & 15;
    const int s0 = blockIdx.x * 128, n = blockIdx.y, kh = blockIdx.z;

    const size_t baseQ = ((size_t)n * S_LEN + s0) * DHEAD;
    const size_t baseK = ((size_t)n * S_LEN + kh * 1024) * DHEAD;
    const size_t baseV = (size_t)n * DHEAD * S_LEN + kh * 1024;

    #pragma unroll
    for (int it = 0; it < 4; it++) {
        int c = tid + it * 256, r = c >> 3, g = c & 7;
        *(uint4*)(pool + r * 64 + ((g ^ (r & 7)) * 8)) =
            *(const uint4*)(Q + baseQ + r * DHEAD + g * 8);
    }
    __syncthreads();
    const int xa = ((0 + quad) ^ (l16 & 7)) * 8;
    const int xb = ((4 + quad) ^ (l16 & 7)) * 8;
    bf16x8 qa[2][2];
    #pragma unroll
    for (int s = 0; s < 2; s++) {
        const int row = w * 32 + s * 16 + l16;
        qa[s][0] = *(const bf16x8*)(pool + row * 64 + xa);
        qa[s][1] = *(const bf16x8*)(pool + row * 64 + xb);
    }
    __syncthreads();

    union { unsigned u[4]; bf16x8 v; } onesA;
    #pragma unroll
    for (int t = 0; t < 4; t++) onesA.u[t] = 0x3F803F80u;

    f32x4 accO[2][4], accL[2];
    #pragma unroll
    for (int s = 0; s < 2; s++) {
        #pragma unroll
        for (int dt = 0; dt < 4; dt++) accO[s][dt] = (f32x4){0.f, 0.f, 0.f, 0.f};
        accL[s] = (f32x4){0.f, 0.f, 0.f, 0.f};
    }

    const int sr = tid >> 3, sg = tid & 7;
    const int Hh = sg >> 2, vOff = ((sg >> 1) & 1) * 4;
    const int o1 = (2 * sg) & 3, o2 = (2 * sg + 1) & 3;
    uint4 kc[2], vc[2];
    auto loadKV = [&](int k0) {
        kc[0] = *(const uint4*)(K + baseK + (size_t)(k0 + sr) * DHEAD + sg * 8);
        kc[1] = *(const uint4*)(K + baseK + (size_t)(k0 + sr + 32) * DHEAD + sg * 8);
        vc[0] = *(const uint4*)(Vt + baseV + (size_t)sr * S_LEN + k0 + sg * 8);
        vc[1] = *(const uint4*)(Vt + baseV + (size_t)(sr + 32) * S_LEN + k0 + sg * 8);
    };
    auto storeKV = [&](int buf) {
        u16* Kb = pool + buf * 8192;
        u16* Vb = pool + 4096 + buf * 8192;
        const int swk = (sg ^ (sr & 7)) * 8;
        *(uint4*)(Kb + sr * 64 + swk)        = kc[0];
        *(uint4*)(Kb + (sr + 32) * 64 + swk) = kc[1];
        const int a1 = ((Hh * 4 + o1) ^ (sr & 7)) * 8 + vOff;
        const int a2 = ((Hh * 4 + o2) ^ (sr & 7)) * 8 + vOff;
        *(uint2*)(Vb + sr * 64 + a1)        = (uint2){vc[0].x, vc[0].y};
        *(uint2*)(Vb + sr * 64 + a2)        = (uint2){vc[0].z, vc[0].w};
        *(uint2*)(Vb + (sr + 32) * 64 + a1) = (uint2){vc[1].x, vc[1].y};
        *(uint2*)(Vb + (sr + 32) * 64 + a2) = (uint2){vc[1].z, vc[1].w};
    };

    loadKV(0);
    storeKV(0);
    __syncthreads();

    for (int i = 0; i < 16; i++) {
        const int buf = i & 1;
        const u16* Kbf = pool + buf * 8192;
        const u16* Vbf = pool + 4096 + buf * 8192;
        if (i < 15) loadKV((i + 1) * 64);

        f32x4 sc[2][4];
        #pragma unroll
        for (int kt = 0; kt < 4; kt++) {
            const int kr = kt * 16 + l16;
            bf16x8 kb0 = *(const bf16x8*)(Kbf + kr * 64 + xa);
            bf16x8 kb1 = *(const bf16x8*)(Kbf + kr * 64 + xb);
            #pragma unroll
            for (int s = 0; s < 2; s++) {
                f32x4 z = (f32x4){0.f, 0.f, 0.f, 0.f};
                z = __builtin_amdgcn_mfma_f32_16x16x32_bf16(kb0, qa[s][0], z, 0, 0, 0);
                z = __builtin_amdgcn_mfma_f32_16x16x32_bf16(kb1, qa[s][1], z, 0, 0, 0);
                sc[s][kt] = z;
            }
        }

        union { unsigned u[4]; bf16x8 v; } pb[2][2];
        #pragma unroll
        for (int s = 0; s < 2; s++) {
            #pragma unroll
            for (int kt = 0; kt < 4; kt++) {
                float p0 = __builtin_amdgcn_exp2f(sc[s][kt][0] - 20.0f);
                float p1 = __builtin_amdgcn_exp2f(sc[s][kt][1] - 20.0f);
                float p2 = __builtin_amdgcn_exp2f(sc[s][kt][2] - 20.0f);
                float p3 = __builtin_amdgcn_exp2f(sc[s][kt][3] - 20.0f);
                pb[s][kt >> 1].u[(kt & 1) * 2 + 0] =
                    __builtin_amdgcn_perm(__float_as_uint(p1), __float_as_uint(p0), 0x07060302u);
                pb[s][kt >> 1].u[(kt & 1) * 2 + 1] =
                    __builtin_amdgcn_perm(__float_as_uint(p3), __float_as_uint(p2), 0x07060302u);
            }
        }

        #pragma unroll
        for (int s = 0; s < 2; s++) {
            accL[s] = __builtin_amdgcn_mfma_f32_16x16x32_bf16(onesA.v, pb[s][0].v, accL[s], 0, 0, 0);
            accL[s] = __builtin_amdgcn_mfma_f32_16x16x32_bf16(onesA.v, pb[s][1].v, accL[s], 0, 0, 0);
        }

        #pragma unroll
        for (int dt = 0; dt < 4; dt++) {
            const int vr = dt * 16 + l16;
            bf16x8 va0 = *(const bf16x8*)(Vbf + vr * 64 + xa);
            bf16x8 va1 = *(const bf16x8*)(Vbf + vr * 64 + xb);
            #pragma unroll
            for (int s = 0; s < 2; s++) {
                accO[s][dt] = __builtin_amdgcn_mfma_f32_16x16x32_bf16(va0, pb[s][0].v, accO[s][dt], 0, 0, 0);
                accO[s][dt] = __builtin_amdgcn_mfma_f32_16x16x32_bf16(va1, pb[s][1].v, accO[s][dt], 0, 0, 0);
            }
        }

        if (i < 15) { storeKV(1 - buf); __syncthreads(); }
    }

    const int bI = n >> 3, h = n & 7;
    u16* Ob = Opart + (size_t)kh * (8192 * 512);
    #pragma unroll
    for (int s = 0; s < 2; s++) {
        const int qg = s0 + w * 32 + s * 16 + l16;
        if (quad == 0)
            Lpart[(size_t)kh * 65536 + n * 2048 + qg] = accL[s][0];
        const size_t base = (size_t)(qg * BATCH + bI) * FDIM + h * DHEAD;
        #pragma unroll
        for (int dt = 0; dt < 4; dt++) {
            ushort4 st = {f2bf(accO[s][dt][0]), f2bf(accO[s][dt][1]),
                          f2bf(accO[s][dt][2]), f2bf(accO[s][dt][3])};
            *(ushort4*)(Ob + base + dt * 16 + quad * 4) = st;
        }
    }
}

// ---------- combine split-K partials (round-13 verbatim) ----------
__global__ __launch_bounds__(256) void combine_k(
    const u16* __restrict__ O, const float* __restrict__ L, u16* __restrict__ Yb)
{
    const int idx = blockIdx.x * 256 + threadIdx.x;   // 4-elem group index
    const int m = idx >> 7, c4 = idx & 127;
    const int g = c4 * 4, h = g >> 6;
    const int q = m >> 2, b = m & 3, n = b * 8 + h;
    const float l = L[n * 2048 + q] + L[65536 + n * 2048 + q];
    const float inv = 1.0f / l;
    const ushort4 o0 = *(const ushort4*)(O + (size_t)m * 512 + g);
    const ushort4 o1 = *(const ushort4*)(O + 4194304u + (size_t)m * 512 + g);
    ushort4 r = {f2bf((bf2f(o0.x) + bf2f(o1.x)) * inv),
                 f2bf((bf2f(o0.y) + bf2f(o1.y)) * inv),
                 f2bf((bf2f(o0.z) + bf2f(o1.z)) * inv),
                 f2bf((bf2f(o0.w) + bf2f(o1.w)) * inv)};
    *(ushort4*)(Yb + (size_t)m * 512 + g) = r;
}

extern "C" void kernel_launch(void* const* d_in, const int* in_sizes, int n_in,
                              void* d_out, int out_size, void* d_ws, size_t ws_size,
                              hipStream_t stream) {
    const float* q  = (const float*)d_in[0];
    const float* k  = (const float*)d_in[1];
    const float* v  = (const float*)d_in[2];
    const float* Wq = (const float*)d_in[3];
    const float* bq = (const float*)d_in[4];
    const float* Wk = (const float*)d_in[5];
    const float* bk = (const float*)d_in[6];
    const float* Wv = (const float*)d_in[7];
    const float* bv = (const float*)d_in[8];
    const float* Wo = (const float*)d_in[9];
    const float* bo = (const float*)d_in[10];
    float* out = (float*)d_out;

    const int NIN = S_LEN * BATCH * FDIM;    // 4194304
    u16* p = (u16*)d_ws;
    u16* Qb  = p;             p += NIN;      // reused as Yb after flash
    u16* Kb  = p;             p += NIN;
    u16* Vtb = p;             p += NIN;
    u16* Opart = p;           p += 2 * NIN;  // 2 x 4194304 bf16
    float* Lpart = (float*)p;                // 2 x 65536 fp32
    u16* Yb = Qb;                            // alias: Qb dead after flash

    const float QSCALE = 0.125f * 1.4426950408889634f;  // 1/sqrt(D) * log2(e)

    dim3 blk(256);
    dim3 gQKV(S_LEN * BATCH / 128, FDIM / 64, 3);   // (64, 8, 3)
    gemm_qkv<<<gQKV, blk, 0, stream>>>(q, k, v, Wq, Wk, Wv, bq, bk, bv,
                                       Qb, Kb, Vtb, QSCALE);

    dim3 gAttn(S_LEN / 128, 32, 2);                 // (16, 32, 2) = 1024 blocks
    flash_attn_mfma<<<gAttn, blk, 0, stream>>>(Qb, Kb, Vtb, Opart, Lpart);

    combine_k<<<4096, blk, 0, stream>>>(Opart, Lpart, Yb);

    dim3 gOut(S_LEN * BATCH / 128, FDIM / 64);      // (64, 8)
    gemm_out<<<gOut, blk, 0, stream>>>(Yb, Wo, bo, out);
}